// Round 7
// baseline (44.747 us; speedup 1.0000x reference)
//
#include <hip/hip_runtime.h>
#include <stdint.h>

#define BATCH 128
#define MAXN 1024
#define NF 9
#define DIM 256
#define NCLS 10

// Combined-table layout (rows of 256):
//  sec0: [0,119)    field0
//  sec1: [119,179)  fields1,2   idx = i1*12+i2
//  sec2: [179,299)  fields3,4   idx = i3*10+i4
//  sec3: [299,443)  fields5..8  idx = ((i5*6+i6)*2+i7)*2+i8
#define BASE1 119
#define BASE2 179
#define BASE3 299
#define QROWS 443

typedef __attribute__((ext_vector_type(4))) float f32x4;
typedef __attribute__((ext_vector_type(2))) uint32_t u32x2;

__device__ __forceinline__ ushort f32_to_bf16_rne(float x) {
  uint32_t u = __float_as_uint(x);
  u += 0x7fffu + ((u >> 16) & 1u);
  return (ushort)(u >> 16);
}

__device__ __forceinline__ f32x4 bf4_to_f32x4(u32x2 v) {
  f32x4 r;
  r.x = __uint_as_float(v.x << 16);
  r.y = __uint_as_float(v.x & 0xffff0000u);
  r.z = __uint_as_float(v.y << 16);
  r.w = __uint_as_float(v.y & 0xffff0000u);
  return r;
}

// ---------------------------------------------------------------------------
// Prep (unchanged, proven ~3us): 4 table rows per block, one W sweep amortized.
//  bid in [0,3):    class rows (f32): clsT[c][o] = lin_b[o] + W2[o]·rxn_emb[c]
//  bid in [3,114):  Q rows (bf16):    Q[q][o]    = W1[o]·S_q
// S_q = sum of 1-4 atom_emb rows (linear layer distributes over the sum).
// ---------------------------------------------------------------------------
__global__ __launch_bounds__(256) void prep_kernel(
    const float* __restrict__ rxn_emb, const float* __restrict__ lin_w,
    const float* __restrict__ lin_b, const float* __restrict__ atom_emb,
    ushort* __restrict__ Qb, float* __restrict__ clsT)
{
  __shared__ float S[4][DIM];
  const int bid = blockIdx.x;
  const int t = threadIdx.x;
  const bool isCls = bid < 3;
  const int row0 = isCls ? bid * 4 : (bid - 3) * 4;
  const int rmax = isCls ? NCLS : QROWS;
  const int nrows = (rmax - row0 < 4) ? (rmax - row0) : 4;

#pragma unroll
  for (int r = 0; r < 4; ++r) {
    float v = 0.f;
    if (r < nrows) {
      const int q = row0 + r;
      if (isCls) {
        v = rxn_emb[q * DIM + t];
      } else if (q < BASE1) {
        v = atom_emb[q * DIM + t];
      } else if (q < BASE2) {
        int x = q - BASE1;
        v = atom_emb[(119 + x / 12) * DIM + t] + atom_emb[(124 + x % 12) * DIM + t];
      } else if (q < BASE3) {
        int x = q - BASE2;
        v = atom_emb[(136 + x / 10) * DIM + t] + atom_emb[(148 + x % 10) * DIM + t];
      } else {
        int x = q - BASE3;
        int i8 = x & 1, i7 = (x >> 1) & 1, y = x >> 2;
        v = atom_emb[(158 + y / 6) * DIM + t] + atom_emb[(164 + y % 6) * DIM + t]
          + atom_emb[(170 + i7) * DIM + t] + atom_emb[(172 + i8) * DIM + t];
      }
    }
    S[r][t] = v;
  }
  __syncthreads();

  const float* wrow = lin_w + (size_t)t * 2 * DIM + (isCls ? DIM : 0);
  const float init = isCls ? lin_b[t] : 0.f;
  float a0 = init, a1 = init, a2 = init, a3 = init;
#pragma unroll 4
  for (int d = 0; d < DIM; d += 4) {
    float4 w4 = *(const float4*)(wrow + d);
    a0 += w4.x * S[0][d] + w4.y * S[0][d + 1] + w4.z * S[0][d + 2] + w4.w * S[0][d + 3];
    a1 += w4.x * S[1][d] + w4.y * S[1][d + 1] + w4.z * S[1][d + 2] + w4.w * S[1][d + 3];
    a2 += w4.x * S[2][d] + w4.y * S[2][d + 1] + w4.z * S[2][d + 2] + w4.w * S[2][d + 3];
    a3 += w4.x * S[3][d] + w4.y * S[3][d + 1] + w4.z * S[3][d + 2] + w4.w * S[3][d + 3];
  }
  if (isCls) {
    if (0 < nrows) clsT[(row0 + 0) * DIM + t] = a0;
    if (1 < nrows) clsT[(row0 + 1) * DIM + t] = a1;
    if (2 < nrows) clsT[(row0 + 2) * DIM + t] = a2;
    if (3 < nrows) clsT[(row0 + 3) * DIM + t] = a3;
  } else {
    if (0 < nrows) Qb[(row0 + 0) * DIM + t] = f32_to_bf16_rne(a0);
    if (1 < nrows) Qb[(row0 + 1) * DIM + t] = f32_to_bf16_rne(a1);
    if (2 < nrows) Qb[(row0 + 2) * DIM + t] = f32_to_bf16_rne(a2);
    if (3 < nrows) Qb[(row0 + 3) * DIM + t] = f32_to_bf16_rne(a3);
  }
}

// ---------------------------------------------------------------------------
// Main: 4096 blocks x 256 threads; wave = 8 node slots. SINGLE CHANGE vs
// round 6: __launch_bounds__(256, 8) forces VGPR<=64 (true 8 waves/SIMD —
// rounds 4/6 were VGPR-capped at 4) + in-flight unroll capped at 4 nodes
// (16 gathers = 32 data VGPRs) so the cap fits without spilling.
// bf16 Q, regular cached gathers, nt stores, three wave-uniform paths.
// ---------------------------------------------------------------------------
__global__ __launch_bounds__(256, 8) void main_kernel(
    const int* __restrict__ node_feat, const int* __restrict__ num_nodes,
    const int* __restrict__ rxn_class,
    const ushort* __restrict__ Qb, const float* __restrict__ clsT,
    float* __restrict__ out)
{
  const int tid = threadIdx.x;
  const int lane = tid & 63;
  const int w = __builtin_amdgcn_readfirstlane(tid >> 6);
  const int wid = blockIdx.x * 4 + w;   // 0..16383
  const int b = wid >> 7;               // 128 waves per batch
  const int n0 = (wid & 127) << 3;      // 8 nodes per wave
  const int nn = num_nodes[b];

  const f32x4 cf = ((const f32x4*)clsT)[rxn_class[b] * 64 + lane];
  f32x4* __restrict__ outp = (f32x4*)out + ((size_t)(b * MAXN + n0)) * 64 + lane;

  if (n0 >= nn) {  // fully masked strip
#pragma unroll
    for (int i = 0; i < 8; ++i)
      __builtin_nontemporal_store(cf, outp + i * 64);
    return;
  }

  const int* __restrict__ p = node_feat + (size_t)(b * MAXN + n0) * NF;
  const u32x2* __restrict__ Q2 = (const u32x2*)Qb;

  if (n0 + 8 <= nn) {  // fully valid strip — branch-free, 4 nodes in flight
#pragma unroll 4
    for (int i = 0; i < 8; ++i) {
      const int j0 = p[i * NF + 0];
      const int j1 = BASE1 + p[i * NF + 1] * 12 + p[i * NF + 2];
      const int j2 = BASE2 + p[i * NF + 3] * 10 + p[i * NF + 4];
      const int j3 = BASE3 + ((p[i * NF + 5] * 6 + p[i * NF + 6]) * 2 + p[i * NF + 7]) * 2 + p[i * NF + 8];
      const u32x2 v0 = Q2[j0 * 64 + lane];
      const u32x2 v1 = Q2[j1 * 64 + lane];
      const u32x2 v2 = Q2[j2 * 64 + lane];
      const u32x2 v3 = Q2[j3 * 64 + lane];
      const f32x4 s = (bf4_to_f32x4(v0) + bf4_to_f32x4(v1))
                    + (bf4_to_f32x4(v2) + bf4_to_f32x4(v3));
      __builtin_nontemporal_store(cf + s, outp + i * 64);
    }
    return;
  }

  // partial strip (<=1 per batch): branchless float-mask
#pragma unroll 4
  for (int i = 0; i < 8; ++i) {
    const int j0 = p[i * NF + 0];
    const int j1 = BASE1 + p[i * NF + 1] * 12 + p[i * NF + 2];
    const int j2 = BASE2 + p[i * NF + 3] * 10 + p[i * NF + 4];
    const int j3 = BASE3 + ((p[i * NF + 5] * 6 + p[i * NF + 6]) * 2 + p[i * NF + 7]) * 2 + p[i * NF + 8];
    const u32x2 v0 = Q2[j0 * 64 + lane];
    const u32x2 v1 = Q2[j1 * 64 + lane];
    const u32x2 v2 = Q2[j2 * 64 + lane];
    const u32x2 v3 = Q2[j3 * 64 + lane];
    const float m = (n0 + i < nn) ? 1.f : 0.f;
    const f32x4 s = (bf4_to_f32x4(v0) + bf4_to_f32x4(v1))
                  + (bf4_to_f32x4(v2) + bf4_to_f32x4(v3));
    __builtin_nontemporal_store(cf + m * s, outp + i * 64);
  }
}

extern "C" void kernel_launch(void* const* d_in, const int* in_sizes, int n_in,
                              void* d_out, int out_size, void* d_ws, size_t ws_size,
                              hipStream_t stream) {
  const int* node_feat = (const int*)d_in[0];
  const int* num_nodes = (const int*)d_in[1];
  const int* rxn_class = (const int*)d_in[2];
  const float* atom_emb = (const float*)d_in[3];
  const float* rxn_emb = (const float*)d_in[4];
  const float* lin_w = (const float*)d_in[5];
  const float* lin_b = (const float*)d_in[6];
  float* outp = (float*)d_out;

  // workspace: Qb (443*256 bf16 = 226816 B) | clsT (10*256 f32 = 10240 B)
  ushort* Qb = (ushort*)d_ws;
  float* clsT = (float*)((char*)d_ws + QROWS * DIM * sizeof(ushort));

  prep_kernel<<<3 + (QROWS + 3) / 4, 256, 0, stream>>>(rxn_emb, lin_w, lin_b,
                                                       atom_emb, Qb, clsT);
  main_kernel<<<4096, 256, 0, stream>>>(node_feat, num_nodes, rxn_class,
                                        Qb, clsT, outp);
}

// Round 8
// 42.936 us; speedup vs baseline: 1.0422x; 1.0422x over previous
//
#include <hip/hip_runtime.h>
#include <stdint.h>

#define BATCH 128
#define MAXN 1024
#define NF 9
#define DIM 256
#define NCLS 10

// Combined-table layout (rows of 256):
//  sec0: [0,119)    field0
//  sec1: [119,179)  fields1,2   idx = i1*12+i2
//  sec2: [179,299)  fields3,4   idx = i3*10+i4
//  sec3: [299,443)  fields5..8  idx = ((i5*6+i6)*2+i7)*2+i8
#define BASE1 119
#define BASE2 179
#define BASE3 299
#define QROWS 443

typedef __attribute__((ext_vector_type(4))) float f32x4;
typedef __attribute__((ext_vector_type(2))) uint32_t u32x2;

__device__ __forceinline__ ushort f32_to_bf16_rne(float x) {
  uint32_t u = __float_as_uint(x);
  u += 0x7fffu + ((u >> 16) & 1u);
  return (ushort)(u >> 16);
}

__device__ __forceinline__ f32x4 bf4_to_f32x4(u32x2 v) {
  f32x4 r;
  r.x = __uint_as_float(v.x << 16);
  r.y = __uint_as_float(v.x & 0xffff0000u);
  r.z = __uint_as_float(v.y << 16);
  r.w = __uint_as_float(v.y & 0xffff0000u);
  return r;
}

// ---------------------------------------------------------------------------
// Prep (unchanged, proven ~3us): 4 table rows per block, one W sweep amortized.
//  bid in [0,3):    class rows (f32): clsT[c][o] = lin_b[o] + W2[o]·rxn_emb[c]
//  bid in [3,114):  Q rows (bf16):    Q[q][o]    = W1[o]·S_q
// S_q = sum of 1-4 atom_emb rows (linear layer distributes over the sum).
// ---------------------------------------------------------------------------
__global__ __launch_bounds__(256) void prep_kernel(
    const float* __restrict__ rxn_emb, const float* __restrict__ lin_w,
    const float* __restrict__ lin_b, const float* __restrict__ atom_emb,
    ushort* __restrict__ Qb, float* __restrict__ clsT)
{
  __shared__ float S[4][DIM];
  const int bid = blockIdx.x;
  const int t = threadIdx.x;
  const bool isCls = bid < 3;
  const int row0 = isCls ? bid * 4 : (bid - 3) * 4;
  const int rmax = isCls ? NCLS : QROWS;
  const int nrows = (rmax - row0 < 4) ? (rmax - row0) : 4;

#pragma unroll
  for (int r = 0; r < 4; ++r) {
    float v = 0.f;
    if (r < nrows) {
      const int q = row0 + r;
      if (isCls) {
        v = rxn_emb[q * DIM + t];
      } else if (q < BASE1) {
        v = atom_emb[q * DIM + t];
      } else if (q < BASE2) {
        int x = q - BASE1;
        v = atom_emb[(119 + x / 12) * DIM + t] + atom_emb[(124 + x % 12) * DIM + t];
      } else if (q < BASE3) {
        int x = q - BASE2;
        v = atom_emb[(136 + x / 10) * DIM + t] + atom_emb[(148 + x % 10) * DIM + t];
      } else {
        int x = q - BASE3;
        int i8 = x & 1, i7 = (x >> 1) & 1, y = x >> 2;
        v = atom_emb[(158 + y / 6) * DIM + t] + atom_emb[(164 + y % 6) * DIM + t]
          + atom_emb[(170 + i7) * DIM + t] + atom_emb[(172 + i8) * DIM + t];
      }
    }
    S[r][t] = v;
  }
  __syncthreads();

  const float* wrow = lin_w + (size_t)t * 2 * DIM + (isCls ? DIM : 0);
  const float init = isCls ? lin_b[t] : 0.f;
  float a0 = init, a1 = init, a2 = init, a3 = init;
#pragma unroll 4
  for (int d = 0; d < DIM; d += 4) {
    float4 w4 = *(const float4*)(wrow + d);
    a0 += w4.x * S[0][d] + w4.y * S[0][d + 1] + w4.z * S[0][d + 2] + w4.w * S[0][d + 3];
    a1 += w4.x * S[1][d] + w4.y * S[1][d + 1] + w4.z * S[1][d + 2] + w4.w * S[1][d + 3];
    a2 += w4.x * S[2][d] + w4.y * S[2][d + 1] + w4.z * S[2][d + 2] + w4.w * S[2][d + 3];
    a3 += w4.x * S[3][d] + w4.y * S[3][d + 1] + w4.z * S[3][d + 2] + w4.w * S[3][d + 3];
  }
  if (isCls) {
    if (0 < nrows) clsT[(row0 + 0) * DIM + t] = a0;
    if (1 < nrows) clsT[(row0 + 1) * DIM + t] = a1;
    if (2 < nrows) clsT[(row0 + 2) * DIM + t] = a2;
    if (3 < nrows) clsT[(row0 + 3) * DIM + t] = a3;
  } else {
    if (0 < nrows) Qb[(row0 + 0) * DIM + t] = f32_to_bf16_rne(a0);
    if (1 < nrows) Qb[(row0 + 1) * DIM + t] = f32_to_bf16_rne(a1);
    if (2 < nrows) Qb[(row0 + 2) * DIM + t] = f32_to_bf16_rne(a2);
    if (3 < nrows) Qb[(row0 + 3) * DIM + t] = f32_to_bf16_rne(a3);
  }
}

// ---------------------------------------------------------------------------
// Main: 4096 blocks x 256 threads; wave = 8 node slots. SINGLE CHANGE vs
// round 7: REGULAR stores replace nontemporal stores (A/B isolation). Main
// writes 134MB at only 3.3 TB/s while harness fills hit 6.7 TB/s with plain
// stores — and round 5 proved nt hints can be disastrous on gfx950 (nt loads
// cost +25us). Q-table L2 eviction risk accepted: 227KB table with extreme
// temporal locality vs LRU.
// bf16 Q, regular cached gathers, three wave-uniform paths.
// ---------------------------------------------------------------------------
__global__ __launch_bounds__(256, 8) void main_kernel(
    const int* __restrict__ node_feat, const int* __restrict__ num_nodes,
    const int* __restrict__ rxn_class,
    const ushort* __restrict__ Qb, const float* __restrict__ clsT,
    float* __restrict__ out)
{
  const int tid = threadIdx.x;
  const int lane = tid & 63;
  const int w = __builtin_amdgcn_readfirstlane(tid >> 6);
  const int wid = blockIdx.x * 4 + w;   // 0..16383
  const int b = wid >> 7;               // 128 waves per batch
  const int n0 = (wid & 127) << 3;      // 8 nodes per wave
  const int nn = num_nodes[b];

  const f32x4 cf = ((const f32x4*)clsT)[rxn_class[b] * 64 + lane];
  f32x4* __restrict__ outp = (f32x4*)out + ((size_t)(b * MAXN + n0)) * 64 + lane;

  if (n0 >= nn) {  // fully masked strip
#pragma unroll
    for (int i = 0; i < 8; ++i)
      outp[i * 64] = cf;
    return;
  }

  const int* __restrict__ p = node_feat + (size_t)(b * MAXN + n0) * NF;
  const u32x2* __restrict__ Q2 = (const u32x2*)Qb;

  if (n0 + 8 <= nn) {  // fully valid strip — branch-free, 4 nodes in flight
#pragma unroll 4
    for (int i = 0; i < 8; ++i) {
      const int j0 = p[i * NF + 0];
      const int j1 = BASE1 + p[i * NF + 1] * 12 + p[i * NF + 2];
      const int j2 = BASE2 + p[i * NF + 3] * 10 + p[i * NF + 4];
      const int j3 = BASE3 + ((p[i * NF + 5] * 6 + p[i * NF + 6]) * 2 + p[i * NF + 7]) * 2 + p[i * NF + 8];
      const u32x2 v0 = Q2[j0 * 64 + lane];
      const u32x2 v1 = Q2[j1 * 64 + lane];
      const u32x2 v2 = Q2[j2 * 64 + lane];
      const u32x2 v3 = Q2[j3 * 64 + lane];
      const f32x4 s = (bf4_to_f32x4(v0) + bf4_to_f32x4(v1))
                    + (bf4_to_f32x4(v2) + bf4_to_f32x4(v3));
      outp[i * 64] = cf + s;
    }
    return;
  }

  // partial strip (<=1 per batch): branchless float-mask
#pragma unroll 4
  for (int i = 0; i < 8; ++i) {
    const int j0 = p[i * NF + 0];
    const int j1 = BASE1 + p[i * NF + 1] * 12 + p[i * NF + 2];
    const int j2 = BASE2 + p[i * NF + 3] * 10 + p[i * NF + 4];
    const int j3 = BASE3 + ((p[i * NF + 5] * 6 + p[i * NF + 6]) * 2 + p[i * NF + 7]) * 2 + p[i * NF + 8];
    const u32x2 v0 = Q2[j0 * 64 + lane];
    const u32x2 v1 = Q2[j1 * 64 + lane];
    const u32x2 v2 = Q2[j2 * 64 + lane];
    const u32x2 v3 = Q2[j3 * 64 + lane];
    const float m = (n0 + i < nn) ? 1.f : 0.f;
    const f32x4 s = (bf4_to_f32x4(v0) + bf4_to_f32x4(v1))
                  + (bf4_to_f32x4(v2) + bf4_to_f32x4(v3));
    outp[i * 64] = cf + m * s;
  }
}

extern "C" void kernel_launch(void* const* d_in, const int* in_sizes, int n_in,
                              void* d_out, int out_size, void* d_ws, size_t ws_size,
                              hipStream_t stream) {
  const int* node_feat = (const int*)d_in[0];
  const int* num_nodes = (const int*)d_in[1];
  const int* rxn_class = (const int*)d_in[2];
  const float* atom_emb = (const float*)d_in[3];
  const float* rxn_emb = (const float*)d_in[4];
  const float* lin_w = (const float*)d_in[5];
  const float* lin_b = (const float*)d_in[6];
  float* outp = (float*)d_out;

  // workspace: Qb (443*256 bf16 = 226816 B) | clsT (10*256 f32 = 10240 B)
  ushort* Qb = (ushort*)d_ws;
  float* clsT = (float*)((char*)d_ws + QROWS * DIM * sizeof(ushort));

  prep_kernel<<<3 + (QROWS + 3) / 4, 256, 0, stream>>>(rxn_emb, lin_w, lin_b,
                                                       atom_emb, Qb, clsT);
  main_kernel<<<4096, 256, 0, stream>>>(node_feat, num_nodes, rxn_class,
                                        Qb, clsT, outp);
}